// Round 2
// baseline (725.058 us; speedup 1.0000x reference)
//
#include <hip/hip_runtime.h>
#include <stdint.h>
#include <stddef.h>

// Grouped GEMM (MoE ragged_dot): C[T,N] fp32 = A[T,K] fp32 @ B[widx[s],:,:]^T
// V3: bf16 pre-pass (one fused cvt kernel into workspace; 160MB bf16 operand
// set is L3-resident) + ring-3 LDS pipeline with counted vmcnt (T4): each
// K-step stages tile k+2 via global_load_lds (4 loads/thread), computes tile
// k, then waits vmcnt(4) lgkmcnt(0) + s_barrier -> the newest 4 loads stay in
// flight across the barrier. T2 bank-swizzle: frag ds_read_b128 chunk =
// quad ^ ((row>>1)&3), realized as pre-swizzled GLOBAL source column with
// linear gload_lds dest (both-sides-or-neither). T5 setprio around MFMAs.

typedef __attribute__((ext_vector_type(8))) short short8;   // 8 x bf16
typedef __attribute__((ext_vector_type(4))) float floatx4;  // MFMA acc

constexpr int E_c = 8;
constexpr int T_c = 8192;
constexpr int K_c = 2048;
constexpr int N_c = 4096;
constexpr int BM = 128;
constexpr int BN = 128;
constexpr int BK = 32;                 // K per step (bf16)
constexpr int KSTEPS = K_c / BK;       // 64
constexpr int XTILES = T_c / BM + E_c; // 72 (upper bound incl. ragged pad)
constexpr int YTILES = N_c / BN;       // 32

// two fp32 -> packed bf16x2 (truncation; rel bias ~2^-9, threshold is 2%)
__device__ __forceinline__ uint32_t pack2(float lo, float hi) {
  union { float f; uint32_t u; } a, b;
  a.f = lo; b.f = hi;
  return __builtin_amdgcn_perm(b.u, a.u, 0x07060302u);
}

// ---------------------------------------------------------------------------
// Fused pre-pass: fp32 A then B -> contiguous bf16 workspace.
// ---------------------------------------------------------------------------
__global__ __launch_bounds__(256) void cvt_both_kernel(
    const float* __restrict__ A, const float* __restrict__ Bm,
    ushort* __restrict__ dst) {
  const int n8A = T_c * K_c / 8;              // 2,097,152
  const int n8T = n8A + E_c * N_c * K_c / 8;  // 10,485,760
  int i = blockIdx.x * 256 + threadIdx.x;
  const int stride = gridDim.x * 256;
  for (; i < n8T; i += stride) {
    const float* s =
        (i < n8A) ? A + (size_t)i * 8 : Bm + (size_t)(i - n8A) * 8;
    float4 v0 = ((const float4*)s)[0], v1 = ((const float4*)s)[1];
    int4 o;
    o.x = pack2(v0.x, v0.y); o.y = pack2(v0.z, v0.w);
    o.z = pack2(v1.x, v1.y); o.w = pack2(v1.z, v1.w);
    ((int4*)dst)[i] = o;
  }
}

// ---------------------------------------------------------------------------
__device__ __forceinline__ void gload16(const ushort* g, ushort* l) {
  __builtin_amdgcn_global_load_lds(
      (const __attribute__((address_space(1))) unsigned int*)g,
      (__attribute__((address_space(3))) unsigned int*)l, 16, 0, 0);
}

__global__ __launch_bounds__(256) void grouped_gemm_bf16_kernel(
    const ushort* __restrict__ A, const ushort* __restrict__ B,
    const int* __restrict__ segp, const int* __restrict__ widx,
    float* __restrict__ C) {
  // Ring-3 double... triple-buffer: 6 distinct static arrays (compile-time
  // buffer selection; alias-transparent to the compiler). 8 KB each, 48 KB.
  __shared__ ushort As0[BM * BK], As1[BM * BK], As2[BM * BK];
  __shared__ ushort Bs0[BN * BK], Bs1[BN * BK], Bs2[BN * BK];

  const int t = threadIdx.x;

  // ---- XCD-aware tile remap: xcd = bid&7 owns y in [4*xcd, 4*xcd+4) ----
  const int bid = blockIdx.x;
  const int xcd = bid & 7;
  const int i = bid >> 3;        // 0..287
  const int yl = i / XTILES;     // 0..3
  const int x = i - yl * XTILES; // 0..71
  const int y = xcd * 4 + yl;

  // ---- segment scan: map x -> (segment, row0) ----
  int s = -1, r0i = 0, rendi = 0, acc_t = 0;
#pragma unroll
  for (int e = 0; e < E_c; ++e) {
    int pe = segp[e], pe1 = segp[e + 1];
    int nt = (pe1 - pe + BM - 1) >> 7;
    if (s < 0 && (x - acc_t) < nt) {
      s = e;
      r0i = pe + ((x - acc_t) << 7);
      rendi = pe1;
    }
    acc_t += nt;
  }
  if (s < 0) return;  // idle pad slot (before any barrier: uniform per block)
  const int expert = widx[s];
  const int n0 = y * BN;

  // ---- staging map: issue j covers rows j*64..j*64+63 (4KB each) ----
  // phys 16B chunk (t&3) of row j*64+(t>>2) holds logical chunk
  // (t&3)^((t>>3)&3)  [st-swizzle, involution; read side applies same XOR]
  const int wave = t >> 6;
  const int gc = (((t & 3) ^ ((t >> 3) & 3)) << 3);  // swizzled global col
  int ar0 = r0i + (t >> 2);
  int ar1 = ar0 + 64;
  if (ar0 > T_c - 1) ar0 = T_c - 1;  // ragged tail: garbage rows, masked store
  if (ar1 > T_c - 1) ar1 = T_c - 1;
  const ushort* Ag0 = A + (size_t)ar0 * K_c + gc;
  const ushort* Ag1 = A + (size_t)ar1 * K_c + gc;
  const ushort* Bg0 = B + ((size_t)expert * N_c + n0 + (t >> 2)) * K_c + gc;
  const ushort* Bg1 = Bg0 + (size_t)64 * K_c;
  const int lo0 = wave * 512;         // LDS ushort base, issue 0 (wave-uniform)
  const int lo1 = 2048 + wave * 512;  // issue 1

  // ---- fragment read indices (swizzled chunk) ----
  const int lane = t & 63;
  const int m16 = lane & 15;
  const int quad = lane >> 4;
  const int csw = (quad ^ ((m16 >> 1) & 3)) << 3;  // swizzled ushort offset
  const int wm = (wave & 1) << 6;
  const int wn = (wave >> 1) << 6;
  int ia[4], ib[4];
#pragma unroll
  for (int q = 0; q < 4; ++q) {
    ia[q] = (wm + q * 16 + m16) * BK + csw;
    ib[q] = (wn + q * 16 + m16) * BK + csw;
  }

  floatx4 acc[4][4];
#pragma unroll
  for (int p = 0; p < 4; ++p)
#pragma unroll
    for (int q = 0; q < 4; ++q) acc[p][q] = (floatx4){0.f, 0.f, 0.f, 0.f};

#define STAGE(Asb, Bsb, kc)                                              \
  {                                                                      \
    const int ko = (kc)*BK;                                              \
    gload16(Ag0 + ko, (Asb) + lo0);                                      \
    gload16(Ag1 + ko, (Asb) + lo1);                                      \
    gload16(Bg0 + ko, (Bsb) + lo0);                                      \
    gload16(Bg1 + ko, (Bsb) + lo1);                                      \
  }

#define COMPUTE(Asb, Bsb)                                                \
  {                                                                      \
    short8 aF[4], bF[4];                                                 \
    _Pragma("unroll") for (int q = 0; q < 4; ++q) {                      \
      aF[q] = *(const short8*)&(Asb)[ia[q]];                             \
      bF[q] = *(const short8*)&(Bsb)[ib[q]];                             \
    }                                                                    \
    __builtin_amdgcn_s_setprio(1);                                       \
    _Pragma("unroll") for (int p = 0; p < 4; ++p)                        \
        _Pragma("unroll") for (int q = 0; q < 4; ++q) acc[p][q] =        \
        __builtin_amdgcn_mfma_f32_16x16x32_bf16(aF[p], bF[q], acc[p][q], \
                                                0, 0, 0);                \
    __builtin_amdgcn_s_setprio(0);                                       \
  }

  // counted drain: newest STAGE's 4 loads stay in flight across the barrier;
  // lgkmcnt(0) retires this step's ds_reads before anyone re-stages that buf.
#define STEPBAR()                                                        \
  asm volatile("s_waitcnt vmcnt(4) lgkmcnt(0)" ::: "memory");            \
  __builtin_amdgcn_s_barrier();

  // ---- prologue: tiles 0,1 staged; wait tile 0 landed (4 newest in flight)
  STAGE(As0, Bs0, 0);
  STAGE(As1, Bs1, 1);
  asm volatile("s_waitcnt vmcnt(4)" ::: "memory");
  __builtin_amdgcn_s_barrier();

  // ---- ring-3 pipelined K loop: step k computes buf[k%3], stages k+2 ----
#pragma unroll 1
  for (int k = 0; k < KSTEPS - 1; k += 3) {  // 21 triples, steps 0..62
    STAGE(As2, Bs2, k + 2);
    COMPUTE(As0, Bs0);
    STEPBAR();
    STAGE(As0, Bs0, (k + 3 < KSTEPS) ? k + 3 : KSTEPS - 1);
    COMPUTE(As1, Bs1);
    STEPBAR();
    STAGE(As1, Bs1, (k + 4 < KSTEPS) ? k + 4 : KSTEPS - 1);
    COMPUTE(As2, Bs2);
    STEPBAR();
  }
  // epilogue: step 63 (63%3==0 -> buf0; staged at k=60 sub1, landed by the
  // final STEPBAR's vmcnt(4))
  COMPUTE(As0, Bs0);

#undef STAGE
#undef COMPUTE
#undef STEPBAR

  // ---- epilogue: C/D layout col=lane&15, row=quad*4+reg ----
#pragma unroll
  for (int p = 0; p < 4; ++p) {
    int growb = r0i + wm + p * 16 + quad * 4;
#pragma unroll
    for (int q = 0; q < 4; ++q) {
      int gcol = n0 + wn + q * 16 + m16;
#pragma unroll
      for (int rr = 0; rr < 4; ++rr) {
        int grow = growb + rr;
        if (grow < rendi) C[(size_t)grow * N_c + gcol] = acc[p][q][rr];
      }
    }
  }
}

// ---------------------------------------------------------------------------
// Fallback (verified r0 kernel): fused fp32->bf16 staging, only if ws too
// small for the bf16 copies.
// ---------------------------------------------------------------------------
constexpr int LSTR = 5;

__device__ __forceinline__ void cvt16(const float4* p, int4* c0, int4* c1) {
  c0->x = pack2(p[0].x, p[0].y); c0->y = pack2(p[0].z, p[0].w);
  c0->z = pack2(p[1].x, p[1].y); c0->w = pack2(p[1].z, p[1].w);
  c1->x = pack2(p[2].x, p[2].y); c1->y = pack2(p[2].z, p[2].w);
  c1->z = pack2(p[3].x, p[3].y); c1->w = pack2(p[3].z, p[3].w);
}

__global__ __launch_bounds__(256) void grouped_gemm_fallback(
    const float* __restrict__ A, const float* __restrict__ B,
    const int* __restrict__ segp, const int* __restrict__ widx,
    float* __restrict__ C) {
  __shared__ int4 As[BM * LSTR];
  __shared__ int4 Bs[BN * LSTR];

  const int t = threadIdx.x;
  const int bid = blockIdx.x;
  const int xcd = bid & 7;
  const int i = bid >> 3;
  const int yl = i / XTILES;
  const int x = i - yl * XTILES;
  const int y = xcd * 4 + yl;

  int s = -1, r0i = 0, rendi = 0, acc_t = 0;
#pragma unroll
  for (int e = 0; e < E_c; ++e) {
    int pe = segp[e], pe1 = segp[e + 1];
    int nt = (pe1 - pe + BM - 1) >> 7;
    if (s < 0 && (x - acc_t) < nt) {
      s = e;
      r0i = pe + ((x - acc_t) << 7);
      rendi = pe1;
    }
    acc_t += nt;
  }
  if (s < 0) return;
  const int expert = widx[s];
  const int n0 = y * BN;

  const int r = t >> 1;
  const int h = t & 1;
  int arow = r0i + r;
  if (arow > T_c - 1) arow = T_c - 1;
  const float* Abase = A + (size_t)arow * K_c + h * 16;
  const float* Bbase = B + ((size_t)expert * N_c + n0 + r) * K_c + h * 16;
  const int wI = r * LSTR + 2 * h;

  const int lane = t & 63;
  const int wave = t >> 6;
  const int m16 = lane & 15;
  const int quad = lane >> 4;
  const int wm = (wave & 1) << 6;
  const int wn = (wave >> 1) << 6;
  int ia[4], ib[4];
#pragma unroll
  for (int q = 0; q < 4; ++q) {
    ia[q] = (wm + q * 16 + m16) * LSTR + quad;
    ib[q] = (wn + q * 16 + m16) * LSTR + quad;
  }

  floatx4 acc[4][4];
#pragma unroll
  for (int p = 0; p < 4; ++p)
#pragma unroll
    for (int q = 0; q < 4; ++q) acc[p][q] = (floatx4){0.f, 0.f, 0.f, 0.f};

  float4 pa[4], pb[4];
#pragma unroll
  for (int j = 0; j < 4; ++j) {
    pa[j] = ((const float4*)Abase)[j];
    pb[j] = ((const float4*)Bbase)[j];
  }

#pragma unroll 1
  for (int kt = 0; kt < 64; ++kt) {
    __syncthreads();
    int4 a0, a1, b0, b1;
    cvt16(pa, &a0, &a1);
    cvt16(pb, &b0, &b1);
    As[wI] = a0; As[wI + 1] = a1;
    Bs[wI] = b0; Bs[wI + 1] = b1;
    __syncthreads();

    const int knext = (kt + 1 < 64) ? kt + 1 : 63;
    const float* an = Abase + knext * 32;
    const float* bn = Bbase + knext * 32;
#pragma unroll
    for (int j = 0; j < 4; ++j) {
      pa[j] = ((const float4*)an)[j];
      pb[j] = ((const float4*)bn)[j];
    }

    short8 aF[4], bF[4];
#pragma unroll
    for (int q = 0; q < 4; ++q) {
      aF[q] = *(const short8*)&As[ia[q]];
      bF[q] = *(const short8*)&Bs[ib[q]];
    }
#pragma unroll
    for (int p = 0; p < 4; ++p)
#pragma unroll
      for (int q = 0; q < 4; ++q)
        acc[p][q] = __builtin_amdgcn_mfma_f32_16x16x32_bf16(aF[p], bF[q],
                                                            acc[p][q], 0, 0, 0);
  }

#pragma unroll
  for (int p = 0; p < 4; ++p) {
    int growb = r0i + wm + p * 16 + quad * 4;
#pragma unroll
    for (int q = 0; q < 4; ++q) {
      int gcol = n0 + wn + q * 16 + m16;
#pragma unroll
      for (int rr = 0; rr < 4; ++rr) {
        int grow = growb + rr;
        if (grow < rendi) C[(size_t)grow * N_c + gcol] = acc[p][q][rr];
      }
    }
  }
}

// ---------------------------------------------------------------------------
extern "C" void kernel_launch(void* const* d_in, const int* in_sizes, int n_in,
                              void* d_out, int out_size, void* d_ws, size_t ws_size,
                              hipStream_t stream) {
  const float* A = (const float*)d_in[0];
  const float* B = (const float*)d_in[1];
  const int* segp = (const int*)d_in[5];
  const int* widx = (const int*)d_in[6];
  float* C = (float*)d_out;

  const size_t abytes = (size_t)T_c * K_c * 2;        // 32 MB bf16 A
  const size_t bbytes = (size_t)E_c * N_c * K_c * 2;  // 128 MB bf16 B

  if (ws_size >= abytes + bbytes) {
    ushort* Abf = (ushort*)d_ws;
    ushort* Bbf = Abf + (size_t)T_c * K_c;
    cvt_both_kernel<<<2048, 256, 0, stream>>>(A, B, Abf);
    grouped_gemm_bf16_kernel<<<dim3(XTILES * YTILES), 256, 0, stream>>>(
        Abf, Bbf, segp, widx, C);
  } else {
    grouped_gemm_fallback<<<dim3(XTILES * YTILES), 256, 0, stream>>>(
        A, B, segp, widx, C);
  }
}

// Round 4
// 698.970 us; speedup vs baseline: 1.0373x; 1.0373x over previous
//
#include <hip/hip_runtime.h>
#include <stdint.h>
#include <stddef.h>

// Grouped GEMM (MoE ragged_dot): C[T,N] fp32 = A[T,K] fp32 @ B[widx[s],:,:]^T
// V5 (= V4 resubmitted after container-level infra failure; ledger re-audited):
// bf16 pre-pass (fused cvt into workspace; 160MB bf16 set is L3-resident)
// + 256x256 8-wave deep-pipelined GEMM (T3+T4 regime):
//   - ring-4 LDS K-tiles (BK=32, 8x16KB = 128KB): step k computes buf[k%4],
//     stages K-tile k+3 into buf[(k+3)%4] (freed at step k-1's barrier ->
//     issue-time WAR safety, required by global_load_lds).
//   - counted s_waitcnt vmcnt(8) ONCE per K-step (2 steps x 4 loads stay in
//     flight across barriers); raw s_barrier, no __syncthreads -> no vmcnt(0)
//     drain. Prefetch lead = 3 K-steps > HBM latency.
//   - 2 phases/K-step, 16 MFMA each, T5 setprio around MFMA clusters.
//   - T2 swizzle identical to r2-verified geometry (BK=32, 4 chunks/row):
//     phys chunk = logical ^ ((row%16)>>1 & 3), realized as pre-swizzled
//     GLOBAL source column + linear gload_lds dest; frag reads apply the
//     same XOR. (r2 measured SQ_LDS_BANK_CONFLICT == 0 with this exact map.)

typedef __attribute__((ext_vector_type(8))) short short8;   // 8 x bf16
typedef __attribute__((ext_vector_type(4))) float floatx4;  // MFMA acc

constexpr int E_c = 8;
constexpr int T_c = 8192;
constexpr int K_c = 2048;
constexpr int N_c = 4096;

// main-kernel geometry
constexpr int BM = 256;
constexpr int BN = 256;
constexpr int BK = 32;                  // K per step
constexpr int NK = K_c / BK;            // 64 steps
constexpr int XTILES = T_c / BM + E_c;  // 40 (upper bound incl. ragged pad)
constexpr int YTILES = N_c / BN;        // 16
constexpr int TSZ = BM * BK;            // 8192 ushorts = 16KB per tile buffer

// two fp32 -> packed bf16x2 (truncation; rel bias ~2^-9, threshold is 2%)
__device__ __forceinline__ uint32_t pack2(float lo, float hi) {
  union { float f; uint32_t u; } a, b;
  a.f = lo; b.f = hi;
  return __builtin_amdgcn_perm(b.u, a.u, 0x07060302u);
}

// ---------------------------------------------------------------------------
// Fused pre-pass: fp32 A then B -> contiguous bf16 workspace.
// ---------------------------------------------------------------------------
__global__ __launch_bounds__(256) void cvt_both_kernel(
    const float* __restrict__ A, const float* __restrict__ Bm,
    ushort* __restrict__ dst) {
  const int n8A = T_c * K_c / 8;
  const int n8T = n8A + E_c * N_c * K_c / 8;
  int i = blockIdx.x * 256 + threadIdx.x;
  const int stride = gridDim.x * 256;
  for (; i < n8T; i += stride) {
    const float* s =
        (i < n8A) ? A + (size_t)i * 8 : Bm + (size_t)(i - n8A) * 8;
    float4 v0 = ((const float4*)s)[0], v1 = ((const float4*)s)[1];
    int4 o;
    o.x = pack2(v0.x, v0.y); o.y = pack2(v0.z, v0.w);
    o.z = pack2(v1.x, v1.y); o.w = pack2(v1.z, v1.w);
    ((int4*)dst)[i] = o;
  }
}

// ---------------------------------------------------------------------------
__device__ __forceinline__ void gload16(const ushort* g, ushort* l) {
  __builtin_amdgcn_global_load_lds(
      (const __attribute__((address_space(1))) unsigned int*)g,
      (__attribute__((address_space(3))) unsigned int*)l, 16, 0, 0);
}

__global__ __launch_bounds__(512, 2) void grouped_gemm_bf16_kernel(
    const ushort* __restrict__ A, const ushort* __restrict__ B,
    const int* __restrict__ segp, const int* __restrict__ widx,
    float* __restrict__ C) {
  // ring-4 K-tile buffers, 16KB each (256 rows x 32 bf16), 128KB total
  // (within gfx950's 160KB; same budget as the m201 template kernel)
  __shared__ ushort As0[TSZ], As1[TSZ], As2[TSZ], As3[TSZ];
  __shared__ ushort Bs0[TSZ], Bs1[TSZ], Bs2[TSZ], Bs3[TSZ];

  const int t = threadIdx.x;

  // ---- XCD-aware tile remap: xcd = bid&7 owns y in [2*xcd, 2*xcd+2) ----
  const int bid = blockIdx.x;   // grid = 640 = 8*80, bijective remap
  const int xcd = bid & 7;
  const int bi = bid >> 3;        // 0..79
  const int yl = bi / XTILES;     // 0..1
  const int x = bi - yl * XTILES; // 0..39
  const int y = xcd * 2 + yl;

  // ---- segment scan: map x -> (segment, row0) ----
  int s = -1, r0i = 0, rendi = 0, acc_t = 0;
#pragma unroll
  for (int e = 0; e < E_c; ++e) {
    int pe = segp[e], pe1 = segp[e + 1];
    int nt = (pe1 - pe + BM - 1) >> 8;
    if (s < 0 && (x - acc_t) < nt) {
      s = e;
      r0i = pe + ((x - acc_t) << 8);
      rendi = pe1;
    }
    acc_t += nt;
  }
  if (s < 0) return;  // idle pad slot (uniform per block, before any barrier)
  const int expert = widx[s];
  const int n0 = y * BN;

  // ---- staging map (identical per-issue geometry to verified r2) ----
  // one gload issue = 1KB = 16 rows of 64B; lane l -> row base+(l>>2),
  // phys chunk (l&3); logical chunk = (l&3) ^ ((l>>3)&3) -> pre-swizzled
  // global column. Wave w stages rows [w*16, w*16+16) (j=0) and +128 (j=1).
  const int w = t >> 6;
  const int lane = t & 63;
  const int rl = lane >> 2;
  const int gc = (((lane & 3) ^ ((lane >> 3) & 3)) << 3);
  int arA0 = r0i + w * 16 + rl;
  int arA1 = arA0 + 128;
  if (arA0 > T_c - 1) arA0 = T_c - 1;  // ragged tail: garbage rows, masked store
  if (arA1 > T_c - 1) arA1 = T_c - 1;
  const ushort* AgJ0 = A + (size_t)arA0 * K_c + gc;
  const ushort* AgJ1 = A + (size_t)arA1 * K_c + gc;
  const ushort* BgJ0 =
      B + ((size_t)expert * N_c + n0 + w * 16 + rl) * K_c + gc;
  const ushort* BgJ1 = BgJ0 + (size_t)128 * K_c;
  const int lw0 = w * 512;         // wave-uniform LDS ushort base, rows 0-127
  const int lw1 = 4096 + w * 512;  // rows 128-255

  // ---- fragment read indices (swizzled chunk; same map as r2) ----
  const int m16 = lane & 15;
  const int quad = lane >> 4;
  const int csw = (quad ^ ((m16 >> 1) & 3)) << 3;
  const int wr = w >> 2;  // 0..1  (M half)
  const int wc = w & 3;   // 0..3  (N quarter)
  int iaL[4], iaH[4], ib[4];
#pragma unroll
  for (int q = 0; q < 4; ++q) {
    iaL[q] = (wr * 128 + q * 16 + m16) * BK + csw;
    iaH[q] = (wr * 128 + 64 + q * 16 + m16) * BK + csw;
    ib[q] = (wc * 64 + q * 16 + m16) * BK + csw;
  }

  floatx4 acc[8][4];
#pragma unroll
  for (int p = 0; p < 8; ++p)
#pragma unroll
    for (int q = 0; q < 4; ++q) acc[p][q] = (floatx4){0.f, 0.f, 0.f, 0.f};

  // stage one K-tile pair (A+B, 4 issues) -- prologue only
#define STAGEPAIR(Asb, Bsb, kt)                                          \
  {                                                                      \
    const size_t ko = (size_t)(kt)*BK;                                   \
    gload16(AgJ0 + ko, (Asb) + lw0);                                     \
    gload16(AgJ1 + ko, (Asb) + lw1);                                     \
    gload16(BgJ0 + ko, (Bsb) + lw0);                                     \
    gload16(BgJ1 + ko, (Bsb) + lw1);                                     \
  }

  // one K-step: compute buf (Asb,Bsb), stage K-tile ktn into (Asn,Bsn).
  // Ledger (per wave): end-of-step vmcnt(8) leaves the 8 newest loads in
  // flight (this step's 4 + previous step's 4); everything staging kt<=k+1
  // is retired -> next step's reads are certified after the barrier.
  // WAR: (Asn,Bsn) readers passed step k-1's end barrier before the issue.
#define STEP(Asb, Bsb, Asn, Bsn, ktn)                                    \
  {                                                                      \
    const size_t ko = (size_t)(ktn)*BK;                                  \
    short8 aF[4], bF[4];                                                 \
    _Pragma("unroll") for (int q = 0; q < 4; ++q) {                      \
      aF[q] = *(const short8*)&(Asb)[iaL[q]];                            \
      bF[q] = *(const short8*)&(Bsb)[ib[q]];                             \
    }                                                                    \
    gload16(AgJ0 + ko, (Asn) + lw0);                                     \
    gload16(AgJ1 + ko, (Asn) + lw1);                                     \
    __builtin_amdgcn_s_setprio(1);                                       \
    _Pragma("unroll") for (int p = 0; p < 4; ++p)                        \
        _Pragma("unroll") for (int q = 0; q < 4; ++q) acc[p][q] =        \
        __builtin_amdgcn_mfma_f32_16x16x32_bf16(aF[p], bF[q], acc[p][q], \
                                                0, 0, 0);                \
    __builtin_amdgcn_s_setprio(0);                                       \
    __builtin_amdgcn_s_barrier();                                        \
    short8 aG[4];                                                        \
    _Pragma("unroll") for (int q = 0; q < 4; ++q) aG[q] =                \
        *(const short8*)&(Asb)[iaH[q]];                                  \
    gload16(BgJ0 + ko, (Bsn) + lw0);                                     \
    gload16(BgJ1 + ko, (Bsn) + lw1);                                     \
    __builtin_amdgcn_s_setprio(1);                                       \
    _Pragma("unroll") for (int p = 0; p < 4; ++p)                        \
        _Pragma("unroll") for (int q = 0; q < 4; ++q) acc[p + 4][q] =    \
        __builtin_amdgcn_mfma_f32_16x16x32_bf16(aG[p], bF[q],            \
                                                acc[p + 4][q], 0, 0, 0); \
    __builtin_amdgcn_s_setprio(0);                                       \
    asm volatile("s_waitcnt vmcnt(8)" ::: "memory");                     \
    __builtin_amdgcn_s_barrier();                                        \
  }

  // ---- prologue: stage kt 0,1,2 (12 loads); certify kt0 (8 stay in flight)
  STAGEPAIR(As0, Bs0, 0);
  STAGEPAIR(As1, Bs1, 1);
  STAGEPAIR(As2, Bs2, 2);
  asm volatile("s_waitcnt vmcnt(8)" ::: "memory");
  __builtin_amdgcn_s_barrier();

  // ---- ring-4 K loop, unrolled x4 (compile-time buffer selection) ----
  // tail steps re-stage kt NK-1 into buffers that are provably free and
  // never read again (keeps the 4-issues/step vmcnt ledger exact).
#pragma unroll 1
  for (int kb = 0; kb < NK / 4; ++kb) {
    const int k4 = kb * 4;
    const int n3 = (k4 + 3 < NK) ? k4 + 3 : NK - 1;
    const int n4 = (k4 + 4 < NK) ? k4 + 4 : NK - 1;
    const int n5 = (k4 + 5 < NK) ? k4 + 5 : NK - 1;
    const int n6 = (k4 + 6 < NK) ? k4 + 6 : NK - 1;
    STEP(As0, Bs0, As3, Bs3, n3);
    STEP(As1, Bs1, As0, Bs0, n4);
    STEP(As2, Bs2, As1, Bs1, n5);
    STEP(As3, Bs3, As2, Bs2, n6);
  }

#undef STAGEPAIR
#undef STEP

  // ---- epilogue: C/D layout col=lane&15, row=quad*4+reg ----
#pragma unroll
  for (int p = 0; p < 8; ++p) {
    int growb = r0i + wr * 128 + p * 16 + quad * 4;
#pragma unroll
    for (int q = 0; q < 4; ++q) {
      int gcol = n0 + wc * 64 + q * 16 + m16;
#pragma unroll
      for (int rr = 0; rr < 4; ++rr) {
        int grow = growb + rr;
        if (grow < rendi) C[(size_t)grow * N_c + gcol] = acc[p][q][rr];
      }
    }
  }
}

// ---------------------------------------------------------------------------
// Fallback (verified r0 kernel): fused fp32->bf16 staging, only if ws too
// small for the bf16 copies.
// ---------------------------------------------------------------------------
constexpr int FBM = 128;
constexpr int FXT = T_c / FBM + E_c;  // 72
constexpr int FYT = N_c / FBM;        // 32
constexpr int LSTR = 5;

__device__ __forceinline__ void cvt16(const float4* p, int4* c0, int4* c1) {
  c0->x = pack2(p[0].x, p[0].y); c0->y = pack2(p[0].z, p[0].w);
  c0->z = pack2(p[1].x, p[1].y); c0->w = pack2(p[1].z, p[1].w);
  c1->x = pack2(p[2].x, p[2].y); c1->y = pack2(p[2].z, p[2].w);
  c1->z = pack2(p[3].x, p[3].y); c1->w = pack2(p[3].z, p[3].w);
}

__global__ __launch_bounds__(256) void grouped_gemm_fallback(
    const float* __restrict__ A, const float* __restrict__ B,
    const int* __restrict__ segp, const int* __restrict__ widx,
    float* __restrict__ C) {
  __shared__ int4 As[FBM * LSTR];
  __shared__ int4 Bs[FBM * LSTR];

  const int t = threadIdx.x;
  const int bid = blockIdx.x;
  const int xcd = bid & 7;
  const int i = bid >> 3;
  const int yl = i / FXT;
  const int x = i - yl * FXT;
  const int y = xcd * 4 + yl;

  int s = -1, r0i = 0, rendi = 0, acc_t = 0;
#pragma unroll
  for (int e = 0; e < E_c; ++e) {
    int pe = segp[e], pe1 = segp[e + 1];
    int nt = (pe1 - pe + FBM - 1) >> 7;
    if (s < 0 && (x - acc_t) < nt) {
      s = e;
      r0i = pe + ((x - acc_t) << 7);
      rendi = pe1;
    }
    acc_t += nt;
  }
  if (s < 0) return;
  const int expert = widx[s];
  const int n0 = y * FBM;

  const int r = t >> 1;
  const int h = t & 1;
  int arow = r0i + r;
  if (arow > T_c - 1) arow = T_c - 1;
  const float* Abase = A + (size_t)arow * K_c + h * 16;
  const float* Bbase = B + ((size_t)expert * N_c + n0 + r) * K_c + h * 16;
  const int wI = r * LSTR + 2 * h;

  const int lane = t & 63;
  const int wave = t >> 6;
  const int m16 = lane & 15;
  const int quad = lane >> 4;
  const int wm = (wave & 1) << 6;
  const int wn = (wave >> 1) << 6;
  int ia[4], ib2[4];
#pragma unroll
  for (int q = 0; q < 4; ++q) {
    ia[q] = (wm + q * 16 + m16) * LSTR + quad;
    ib2[q] = (wn + q * 16 + m16) * LSTR + quad;
  }

  floatx4 acc[4][4];
#pragma unroll
  for (int p = 0; p < 4; ++p)
#pragma unroll
    for (int q = 0; q < 4; ++q) acc[p][q] = (floatx4){0.f, 0.f, 0.f, 0.f};

  float4 pa[4], pb[4];
#pragma unroll
  for (int j = 0; j < 4; ++j) {
    pa[j] = ((const float4*)Abase)[j];
    pb[j] = ((const float4*)Bbase)[j];
  }

#pragma unroll 1
  for (int kt = 0; kt < 64; ++kt) {
    __syncthreads();
    int4 a0, a1, b0, b1;
    cvt16(pa, &a0, &a1);
    cvt16(pb, &b0, &b1);
    As[wI] = a0; As[wI + 1] = a1;
    Bs[wI] = b0; Bs[wI + 1] = b1;
    __syncthreads();

    const int knext = (kt + 1 < 64) ? kt + 1 : 63;
    const float* an = Abase + knext * 32;
    const float* bn = Bbase + knext * 32;
#pragma unroll
    for (int j = 0; j < 4; ++j) {
      pa[j] = ((const float4*)an)[j];
      pb[j] = ((const float4*)bn)[j];
    }

    short8 aF[4], bF[4];
#pragma unroll
    for (int q = 0; q < 4; ++q) {
      aF[q] = *(const short8*)&As[ia[q]];
      bF[q] = *(const short8*)&Bs[ib2[q]];
    }
#pragma unroll
    for (int p = 0; p < 4; ++p)
#pragma unroll
      for (int q = 0; q < 4; ++q)
        acc[p][q] = __builtin_amdgcn_mfma_f32_16x16x32_bf16(aF[p], bF[q],
                                                            acc[p][q], 0, 0, 0);
  }

#pragma unroll
  for (int p = 0; p < 4; ++p) {
    int growb = r0i + wm + p * 16 + quad * 4;
#pragma unroll
    for (int q = 0; q < 4; ++q) {
      int gcol = n0 + wn + q * 16 + m16;
#pragma unroll
      for (int rr = 0; rr < 4; ++rr) {
        int grow = growb + rr;
        if (grow < rendi) C[(size_t)grow * N_c + gcol] = acc[p][q][rr];
      }
    }
  }
}

// ---------------------------------------------------------------------------
extern "C" void kernel_launch(void* const* d_in, const int* in_sizes, int n_in,
                              void* d_out, int out_size, void* d_ws, size_t ws_size,
                              hipStream_t stream) {
  const float* A = (const float*)d_in[0];
  const float* B = (const float*)d_in[1];
  const int* segp = (const int*)d_in[5];
  const int* widx = (const int*)d_in[6];
  float* C = (float*)d_out;

  const size_t abytes = (size_t)T_c * K_c * 2;        // 32 MB bf16 A
  const size_t bbytes = (size_t)E_c * N_c * K_c * 2;  // 128 MB bf16 B

  if (ws_size >= abytes + bbytes) {
    ushort* Abf = (ushort*)d_ws;
    ushort* Bbf = Abf + (size_t)T_c * K_c;
    cvt_both_kernel<<<2048, 256, 0, stream>>>(A, B, Abf);
    grouped_gemm_bf16_kernel<<<dim3(XTILES * YTILES), 512, 0, stream>>>(
        Abf, Bbf, segp, widx, C);
  } else {
    grouped_gemm_fallback<<<dim3(FXT * FYT), 256, 0, stream>>>(
        A, B, segp, widx, C);
  }
}